// Round 14
// baseline (72.091 us; speedup 1.0000x reference)
//
#include <hip/hip_runtime.h>

#define AS1 __attribute__((address_space(1)))
#define AS3 __attribute__((address_space(3)))

typedef float f32x4 __attribute__((ext_vector_type(4)));
typedef long lx2 __attribute__((ext_vector_type(2)));
typedef unsigned short u16x4 __attribute__((ext_vector_type(4)));

static constexpr int C = 768;
static constexpr int NB = 128;    // N1 == N2
static constexpr int S  = 256;    // W*H
static constexpr int XY_ELEMS  = NB * NB * S;  // 4194304
static constexpr int XSQ_ELEMS = NB * S;       // 32768
static constexpr size_t WS_TENSOR_B = (size_t)S * NB * C;  // bytes (fp8)

// ---------------------------------------------------------------------------
// Pass 1 (barrier-free register transpose): thread t owns s=t, streams its
// 128-c range with wave-coalesced 256B reads (lanes = consecutive s). NO LDS,
// NO barriers — each wave is an independent pipeline. fp8 pack + 64B k-tile
// bursts with the SAME pre-permuted layout pass2 expects (ws bytes identical
// to R12/R13):
//   slot(u) = 2*((u&3)^sn) + (u>>2), u=(c>>3)&7, kt=c>>6, sn=(n>>1)&3.
// Square-mean: per-thread over its 128 c -> one atomicAdd (6 blocks/target).
// ---------------------------------------------------------------------------
__global__ __launch_bounds__(256) void pass1(const float* __restrict__ x,
                                             const float* __restrict__ y,
                                             unsigned char* __restrict__ xb,
                                             unsigned char* __restrict__ yb,
                                             float* __restrict__ out) {
  const int b    = blockIdx.x;            // 1536 = 8 XCD * 192
  const int x8   = b & 7;                 // XCD
  const int j    = b >> 3;                // 0..191
  const int tensor = j / 96;
  const int r    = j - tensor * 96;
  const int nIdx = r / 6;                 // 0..15
  const int cr   = r - nIdx * 6;          // 0..5 (128-c range)
  const int n    = nIdx * 8 + x8;         // 0..127

  const float*   src = tensor ? y  : x;
  unsigned char* dst = tensor ? yb : xb;
  float*         sqo = out + XY_ELEMS + tensor * XSQ_ELEMS;

  const int t  = threadIdx.x;             // owned s
  const int sn = (n >> 1) & 3;

  // per-c stride S floats; thread offset t
  const float* srcc = src + (size_t)n * (C * S) + (size_t)(cr * 128) * S + t;
  unsigned char* dstrow = dst + (size_t)n * (S * C) + (size_t)t * C;

  float sq = 0.f;
  float fc[16], fn[16];
  uint2 pr[8];                            // 64B k-tile stash (static idx)

  // prologue: group 0 (16 wave-coalesced 256B runs)
#pragma unroll
  for (int i = 0; i < 16; ++i) fc[i] = srcc[(size_t)i * S];

#pragma unroll
  for (int g = 0; g < 8; ++g) {
    if (g < 7) {  // prefetch next 16-c group
#pragma unroll
      for (int i = 0; i < 16; ++i)
        fn[i] = srcc[(size_t)((g + 1) * 16 + i) * S];
    }

#pragma unroll
    for (int i = 0; i < 16; ++i) sq += fc[i] * fc[i];

    // fp8 e4m3 pack: two 8B units -> stash at static indices
    int w0 = __builtin_amdgcn_cvt_pk_fp8_f32(fc[0], fc[1], 0, false);
    w0     = __builtin_amdgcn_cvt_pk_fp8_f32(fc[2], fc[3], w0, true);
    int w1 = __builtin_amdgcn_cvt_pk_fp8_f32(fc[4], fc[5], 0, false);
    w1     = __builtin_amdgcn_cvt_pk_fp8_f32(fc[6], fc[7], w1, true);
    int w2 = __builtin_amdgcn_cvt_pk_fp8_f32(fc[8], fc[9], 0, false);
    w2     = __builtin_amdgcn_cvt_pk_fp8_f32(fc[10], fc[11], w2, true);
    int w3 = __builtin_amdgcn_cvt_pk_fp8_f32(fc[12], fc[13], 0, false);
    w3     = __builtin_amdgcn_cvt_pk_fp8_f32(fc[14], fc[15], w3, true);

    pr[(g & 3) * 2]     = make_uint2((unsigned)w0, (unsigned)w1);
    pr[(g & 3) * 2 + 1] = make_uint2((unsigned)w2, (unsigned)w3);

    if ((g & 3) == 3) {
      // k-tile complete: 64B burst; group q^sn holds units {q, q+4}
      const int kt = cr * 2 + (g >> 2);
#pragma unroll
      for (int q = 0; q < 4; ++q) {
        uint4 v = make_uint4(pr[q].x, pr[q].y, pr[q + 4].x, pr[q + 4].y);
        *reinterpret_cast<uint4*>(dstrow + kt * 64 + ((q ^ sn) * 16)) = v;
      }
    }

#pragma unroll
    for (int i = 0; i < 16; ++i) fc[i] = fn[i];
  }

  atomicAdd(&sqo[n * S + t], sq * (1.0f / 768.0f));
}

// ---------------------------------------------------------------------------
// Pass 2 (frozen from R13): per s, fp8 e4m3 128x128x768 GEMM on [n][s][c] ws;
// epilogue packs RNE bf16 -> ws2b[s][m][n].
// ---------------------------------------------------------------------------
__global__ __launch_bounds__(256) void pass2(const unsigned char* __restrict__ xb,
                                             const unsigned char* __restrict__ yb,
                                             unsigned short* __restrict__ ws2b) {
  const int bid = blockIdx.x;
  const int s = ((bid & 7) << 5) | (bid >> 3);  // XCD-aware, bijective

  const unsigned char* A = xb + (size_t)s * C;  // [n][s][c]: + n*(S*C)
  const unsigned char* B = yb + (size_t)s * C;

  __shared__ unsigned char As[2][128 * 64];
  __shared__ unsigned char Bs[2][128 * 64];

  const int t    = threadIdx.x;
  const int lane = t & 63;
  const int w    = t >> 6;
  const int wn   = w >> 1;
  const int wm   = w & 1;

  const unsigned char* gA[2];
  const unsigned char* gB[2];
  int lo16[2];
#pragma unroll
  for (int i = 0; i < 2; ++i) {
    int ci  = i * 256 + t;
    int row = ci >> 2;                  // n
    int j16 = ci & 3;
    gA[i]   = A + (size_t)row * (S * C) + j16 * 16;
    gB[i]   = B + (size_t)row * (S * C) + j16 * 16;
    lo16[i] = ci * 16;
  }

#define STAGE(K0, BUF)                                                        \
  {                                                                           \
    _Pragma("unroll") for (int i = 0; i < 2; ++i) {                           \
      __builtin_amdgcn_global_load_lds(                                       \
          (const AS1 unsigned int*)(gA[i] + (K0)*64),                         \
          (AS3 unsigned int*)((char*)As[BUF] + lo16[i]), 16, 0, 0);           \
      __builtin_amdgcn_global_load_lds(                                       \
          (const AS1 unsigned int*)(gB[i] + (K0)*64),                         \
          (AS3 unsigned int*)((char*)Bs[BUF] + lo16[i]), 16, 0, 0);           \
    }                                                                         \
  }

  f32x4 acc[4][4] = {};

  STAGE(0, 0);

#pragma unroll
  for (int k0 = 0; k0 < 12; ++k0) {
    if (k0 < 11) STAGE(k0 + 1, (k0 + 1) & 1);

    if (k0 < 11) {
      asm volatile("s_waitcnt vmcnt(4)" ::: "memory");
    } else {
      asm volatile("s_waitcnt vmcnt(0)" ::: "memory");
    }
    __builtin_amdgcn_s_barrier();

    const char* Ab = (const char*)As[k0 & 1];
    const char* Bb = (const char*)Bs[k0 & 1];

    lx2 av[4], bv[4];
    const int q = lane >> 4;
#pragma unroll
    for (int mi = 0; mi < 4; ++mi) {
      int row = wn * 64 + mi * 16 + (lane & 15);
      av[mi] = *reinterpret_cast<const lx2*>(
          Ab + row * 64 + ((q ^ ((row >> 1) & 3)) * 16));
    }
#pragma unroll
    for (int nj = 0; nj < 4; ++nj) {
      int row = wm * 64 + nj * 16 + (lane & 15);
      bv[nj] = *reinterpret_cast<const lx2*>(
          Bb + row * 64 + ((q ^ ((row >> 1) & 3)) * 16));
    }
#pragma unroll
    for (int mi = 0; mi < 4; ++mi)
#pragma unroll
      for (int nj = 0; nj < 4; ++nj) {
        acc[mi][nj] = __builtin_amdgcn_mfma_f32_16x16x32_fp8_fp8(
            av[mi][0], bv[nj][0], acc[mi][nj], 0, 0, 0);
        acc[mi][nj] = __builtin_amdgcn_mfma_f32_16x16x32_fp8_fp8(
            av[mi][1], bv[nj][1], acc[mi][nj], 0, 0, 0);
      }

    if (k0 < 11) __builtin_amdgcn_s_barrier();
  }
#undef STAGE

  const float inv = 1.0f / 768.0f;
  unsigned short* w2 = ws2b + (size_t)s * (NB * NB);
#pragma unroll
  for (int mi = 0; mi < 4; ++mi) {
#pragma unroll
    for (int nj = 0; nj < 4; ++nj) {
      f32x4 v = acc[mi][nj] * inv;
      u16x4 o;
#pragma unroll
      for (int r = 0; r < 4; ++r) {
        unsigned fu = __float_as_uint(v[r]);
        unsigned rr = fu + 0x7fffu + ((fu >> 16) & 1u);  // RNE
        o[r] = (unsigned short)(rr >> 16);
      }
      int mm = wm * 64 + nj * 16 + (lane & 15);
      int nn = wn * 64 + mi * 16 + (lane >> 4) * 4;
      *reinterpret_cast<u16x4*>(w2 + (size_t)mm * NB + nn) = o;
    }
  }
}

// ---------------------------------------------------------------------------
// Pass 3 (frozen from R13): transpose ws2b[s][m][n] (bf16) -> out[n][m][s].
// ---------------------------------------------------------------------------
__global__ __launch_bounds__(256) void pass3(const unsigned short* __restrict__ ws2b,
                                             float* __restrict__ out) {
  const int bid = blockIdx.x;        // 1024 blocks
  const int m   = bid & 127;
  const int st  = (bid >> 7) & 3;
  const int nt  = bid >> 9;          // 0..1
  const int t   = threadIdx.x;
  const int l16 = t & 15;
  const int hi4 = t >> 4;

  __shared__ float tile[64 * 64];    // swizzled [s][nchunk^((s>>2)&15)][4]

  const unsigned short* src =
      ws2b + ((size_t)(st * 64) * NB + m) * NB + nt * 64;
#pragma unroll
  for (int i = 0; i < 4; ++i) {
    int s_local = hi4 + 16 * i;
    uint2 u = *reinterpret_cast<const uint2*>(
        src + (size_t)s_local * (NB * NB) + l16 * 4);
    f32x4 v;
    v[0] = __uint_as_float((u.x & 0xffffu) << 16);
    v[1] = __uint_as_float((u.x >> 16) << 16);
    v[2] = __uint_as_float((u.y & 0xffffu) << 16);
    v[3] = __uint_as_float((u.y >> 16) << 16);
    int chunk = l16 ^ ((s_local >> 2) & 15);
    *reinterpret_cast<f32x4*>(&tile[s_local * 64 + chunk * 4]) = v;
  }
  __syncthreads();

  float* dst = out + ((size_t)(nt * 64) * NB + m) * S + st * 64;
#pragma unroll
  for (int i = 0; i < 4; ++i) {
    int n_local = hi4 + 16 * i;
    int cb      = (n_local >> 2) & 15;
    int ne      = n_local & 3;
    int s4      = l16 * 4;
    f32x4 v;
#pragma unroll
    for (int j = 0; j < 4; ++j) {
      int ss = s4 + j;
      v[j] = tile[ss * 64 + ((cb ^ ((ss >> 2) & 15)) << 2) + ne];
    }
    __builtin_nontemporal_store(
        v, reinterpret_cast<f32x4*>(dst + (size_t)n_local * (NB * S) + s4));
  }
}

extern "C" void kernel_launch(void* const* d_in, const int* in_sizes, int n_in,
                              void* d_out, int out_size, void* d_ws, size_t ws_size,
                              hipStream_t stream) {
  const float* x = (const float*)d_in[0];
  const float* y = (const float*)d_in[1];
  float* out = (float*)d_out;

  unsigned char* xb = (unsigned char*)d_ws;       // [128][256][768] fp8
  unsigned char* yb = xb + WS_TENSOR_B;
  unsigned short* ws2b =
      (unsigned short*)((char*)d_ws + 2 * WS_TENSOR_B);  // [256][128][128] bf16

  // zero xx/yy (atomicAdd target)
  hipMemsetAsync(out + XY_ELEMS, 0, (size_t)2 * XSQ_ELEMS * sizeof(float),
                 stream);
  pass1<<<1536, 256, 0, stream>>>(x, y, xb, yb, out);
  pass2<<<256, 256, 0, stream>>>(xb, yb, ws2b);
  pass3<<<1024, 256, 0, stream>>>(ws2b, out);
}